// Round 8
// baseline (89.224 us; speedup 1.0000x reference)
//
#include <hip/hip_runtime.h>

#define N2 128
#define BLOCK 256        // 4 waves; wave w covers j in [32w, 32w+32)
#define APB 64           // anchors per block (one per lane)
#define BAND 9.5367431640625e-07f   // 2^-20 relative guard band
#define REPS 4           // diagnostic: repeat compute phase to expose steady state

__global__ __launch_bounds__(BLOCK, 8) void matcher_kernel(
    const float4* __restrict__ boxes1,
    const float4* __restrict__ boxes2,
    float* __restrict__ out_vals,
    float* __restrict__ out_idx,
    float* __restrict__ out_labels,
    int n1)
{
#pragma clang fp contract(off)
    __shared__ float4 s_b2[N2];
    __shared__ float  s_area2[N2];
    __shared__ float  s_q[4][APB];
    __shared__ int    s_ix[4][APB];

    const int t = threadIdx.x;
    if (t < N2) {
        const float4 b = boxes2[t];            // (y1, x1, y2, x2)
        s_b2[t] = b;
        s_area2[t] = (b.z - b.x) * (b.w - b.y);
    }
    __syncthreads();

    const int w    = __builtin_amdgcn_readfirstlane(t >> 6); // wave id, uniform
    const int lane = t & 63;
    const int i    = blockIdx.x * APB + lane;

    float4 av = boxes1[(i < n1) ? i : 0];
    const int j0 = w * 32;

    float qe = 0.0f;
    int   bidx = j0;

#define FRAC(J, AREA1, INTER, UM)                                     \
    {                                                                 \
        const float4 b = s_b2[(J)];                                   \
        const float hy = fmaxf(fminf(av.z, b.z) - fmaxf(av.x, b.x), 0.0f); \
        const float hx = fmaxf(fminf(av.w, b.w) - fmaxf(av.y, b.y), 0.0f); \
        INTER = hy * hx;                                              \
        UM = fmaxf(((AREA1) + s_area2[(J)]) - INTER, 1e-10f);         \
    }

#pragma clang loop unroll(disable)
    for (int rep = 0; rep < REPS; ++rep) {
        // defeat CSE across reps: compiler must treat av as modified
        asm volatile("" : "+v"(av.x), "+v"(av.y), "+v"(av.z), "+v"(av.w));

        const float area1 = (av.z - av.x) * (av.w - av.y);

        float bq = -1.0f;
        int   bx = j0;
        bool  slow = false;

#pragma unroll 8
        for (int k = 0; k < 32; ++k) {
            const int j = j0 + k;              // wave-uniform
            const float4 b = boxes2[j];        // uniform -> s_load
            const float a2 = s_area2[j];       // uniform -> LDS broadcast
            const float hy = fmaxf(fminf(av.z, b.z) - fmaxf(av.x, b.x), 0.0f);
            const float hx = fmaxf(fminf(av.w, b.w) - fmaxf(av.y, b.y), 0.0f);
            const float inter = hy * hx;
            const float um = fmaxf((area1 + a2) - inter, 1e-10f);
            const float q   = inter * __builtin_amdgcn_rcpf(um);
            const float d   = q - bq;
            const float th  = bq * BAND;
            slow = slow | ((inter > 0.0f) & (fabsf(d) <= th));
            if (d > th) { bq = q; bx = j; }
        }

        if (slow) {
            // rare: replay this wave's window with exact reference semantics
            float best = -1.0f;
            int   sx = j0;
            for (int k = 0; k < 32; ++k) {
                const int j = j0 + k;
                float inter, um;
                FRAC(j, area1, inter, um)
                const float qq = inter / um;   // exact IEEE divide
                if (qq > best) { best = qq; sx = j; }
            }
            bx = sx;
        }

        // one exact IEEE divide on the winner reproduces matched_val bitwise
        {
            float inter, um;
            FRAC(bx, area1, inter, um)
            qe = inter / um;
        }
        bidx = bx;
    }

    s_q[w][lane]  = qe;
    s_ix[w][lane] = bidx;
    __syncthreads();

    // merge the 4 wave-partials; ascending wave + strict > == first-max
    if (t < APB) {
        const int ii = blockIdx.x * APB + t;
        if (ii < n1) {
            float q  = s_q[0][t];
            int   ix = s_ix[0][t];
#pragma unroll
            for (int w2 = 1; w2 < 4; ++w2) {
                const float q2 = s_q[w2][t];
                if (q2 > q) { q = q2; ix = s_ix[w2][t]; }
            }
            out_vals[ii]   = q;
            out_idx[ii]    = (float)ix;
            out_labels[ii] = (q >= 0.7f) ? 1.0f : ((q < 0.3f) ? 0.0f : -1.0f);
        }
    }
}

extern "C" void kernel_launch(void* const* d_in, const int* in_sizes, int n_in,
                              void* d_out, int out_size, void* d_ws, size_t ws_size,
                              hipStream_t stream) {
    const float4* boxes1 = (const float4*)d_in[0];
    const float4* boxes2 = (const float4*)d_in[1];
    const int n1 = in_sizes[0] / 4;

    float* out = (float*)d_out;
    float* out_vals   = out;
    float* out_idx    = out + n1;
    float* out_labels = out + 2 * n1;

    const int grid = (n1 + APB - 1) / APB;
    matcher_kernel<<<grid, BLOCK, 0, stream>>>(boxes1, boxes2,
                                               out_vals, out_idx, out_labels, n1);
}

// Round 9
// 38.244 us; speedup vs baseline: 2.3330x; 2.3330x over previous
//
#include <hip/hip_runtime.h>

#define N2 128
#define BLOCK 256        // 4 waves; wave w covers j in [32w, 32w+32)
#define APB 64           // anchors per block (one per lane)

__global__ __launch_bounds__(BLOCK, 8) void matcher_kernel(
    const float4* __restrict__ boxes1,
    const float4* __restrict__ boxes2,
    float* __restrict__ out_vals,
    float* __restrict__ out_idx,
    float* __restrict__ out_labels,
    int n1)
{
#pragma clang fp contract(off)
    __shared__ float4 s_b2[N2];
    __shared__ float  s_area2[N2];
    __shared__ float  s_q[4][APB];
    __shared__ int    s_ix[4][APB];

    const int t = threadIdx.x;
    if (t < N2) {
        const float4 b = boxes2[t];            // (y1, x1, y2, x2)
        s_b2[t] = b;
        s_area2[t] = (b.z - b.x) * (b.w - b.y);
    }
    __syncthreads();

    const int w    = __builtin_amdgcn_readfirstlane(t >> 6); // wave id, uniform
    const int lane = t & 63;
    const int i    = blockIdx.x * APB + lane;

    const float4 a = boxes1[(i < n1) ? i : 0];
    const float area1 = (a.z - a.x) * (a.w - a.y);

    const int j0 = w * 32;

    // packed argmax: p = (bits(q) & ~0x7F) | (31-k).  q >= 0 so int order ==
    // float order; low-7 index field is decreasing in k => among equal
    // quantized q the SMALLEST j wins (numpy first-max). Track top-2 to
    // detect when quantization (+/-128ulp) could hide the true exact order.
    int M  = INT_MIN;
    int M2 = INT_MIN;

#pragma unroll 8
    for (int k = 0; k < 32; ++k) {
        const int j = j0 + k;                  // wave-uniform
        const float4 b = boxes2[j];            // uniform -> s_load_dwordx4
        const float a2 = s_area2[j];           // uniform -> LDS broadcast
        const float hy = fmaxf(fminf(a.z, b.z) - fmaxf(a.x, b.x), 0.0f);
        const float hx = fmaxf(fminf(a.w, b.w) - fmaxf(a.y, b.y), 0.0f);
        const float inter = hy * hx;
        const float um = fmaxf((area1 + a2) - inter, 1e-10f);
        const float q = inter * __builtin_amdgcn_rcpf(um);
        const int p = (__float_as_int(q) & 0xFFFFFF80) | (31 - k); // v_and_or_b32
        const int mn = (M < p) ? M : p;        // v_min_i32
        M2 = (M2 > mn) ? M2 : mn;              // v_max_i32  (runner-up)
        M  = (M  > p)  ? M  : p;               // v_max_i32  (winner)
    }

    int bidx = j0 + 31 - (M & 0x7F);
    // ambiguous if winner and runner-up within 2 quantization buckets
    const bool slow = ((M >> 7) - (M2 >> 7)) <= 2;

#define FRAC(J, INTER, UM)                                            \
    {                                                                 \
        const float4 b = s_b2[(J)];                                   \
        const float hy = fmaxf(fminf(a.z, b.z) - fmaxf(a.x, b.x), 0.0f); \
        const float hx = fmaxf(fminf(a.w, b.w) - fmaxf(a.y, b.y), 0.0f); \
        INTER = hy * hx;                                              \
        UM = fmaxf((area1 + s_area2[(J)]) - INTER, 1e-10f);           \
    }

    if (slow) {
        // rare: replay this wave's window with exact reference semantics
        float best = -1.0f;
        int   bx = j0;
        for (int k = 0; k < 32; ++k) {
            const int j = j0 + k;
            float inter, um;
            FRAC(j, inter, um)
            const float qq = inter / um;       // exact IEEE divide
            if (qq > best) { best = qq; bx = j; }
        }
        bidx = bx;
    }

    // one exact IEEE divide on the winner reproduces matched_val bitwise
    float qe;
    {
        float inter, um;
        FRAC(bidx, inter, um)                  // per-lane LDS gather, once
        qe = inter / um;
    }

    s_q[w][lane]  = qe;
    s_ix[w][lane] = bidx;
    __syncthreads();

    // merge the 4 wave-partials; ascending wave + strict > == first-max
    if (t < APB) {
        const int ii = blockIdx.x * APB + t;
        if (ii < n1) {
            float q  = s_q[0][t];
            int   ix = s_ix[0][t];
#pragma unroll
            for (int w2 = 1; w2 < 4; ++w2) {
                const float q2 = s_q[w2][t];
                if (q2 > q) { q = q2; ix = s_ix[w2][t]; }
            }
            out_vals[ii]   = q;
            out_idx[ii]    = (float)ix;
            out_labels[ii] = (q >= 0.7f) ? 1.0f : ((q < 0.3f) ? 0.0f : -1.0f);
        }
    }
}

extern "C" void kernel_launch(void* const* d_in, const int* in_sizes, int n_in,
                              void* d_out, int out_size, void* d_ws, size_t ws_size,
                              hipStream_t stream) {
    const float4* boxes1 = (const float4*)d_in[0];
    const float4* boxes2 = (const float4*)d_in[1];
    const int n1 = in_sizes[0] / 4;

    float* out = (float*)d_out;
    float* out_vals   = out;
    float* out_idx    = out + n1;
    float* out_labels = out + 2 * n1;

    const int grid = (n1 + APB - 1) / APB;
    matcher_kernel<<<grid, BLOCK, 0, stream>>>(boxes1, boxes2,
                                               out_vals, out_idx, out_labels, n1);
}

// Round 10
// 37.386 us; speedup vs baseline: 2.3865x; 1.0229x over previous
//
#include <hip/hip_runtime.h>

#define N2 128
#define BLOCK 256
#define BAND 9.5367431640625e-07f   // 2^-20 relative guard band

__global__ __launch_bounds__(BLOCK, 8) void matcher_kernel(
    const float4* __restrict__ boxes1,
    const float4* __restrict__ boxes2,
    float* __restrict__ out_vals,
    float* __restrict__ out_idx,
    float* __restrict__ out_labels,
    int n1)
{
#pragma clang fp contract(off)
    __shared__ float s_area2[N2];

    const int t = threadIdx.x;
    if (t < N2) {
        const float4 b = boxes2[t];            // (y1, x1, y2, x2)
        s_area2[t] = (b.z - b.x) * (b.w - b.y);
    }
    __syncthreads();

    // one thread = one anchor, scanning ALL 128 gt boxes: no merge phase,
    // no cross-wave staging, waves fully independent after the one sync.
    const int i = blockIdx.x * BLOCK + t;
    const float4 a = boxes1[(i < n1) ? i : 0];
    const float area1 = (a.z - a.x) * (a.w - a.y);

    // two halves (j = k and j = k+64) so the index cndmask uses an
    // inline constant k in [0,63]; top-2 tracked as floats, band test ONCE
    // after the loop (per-lane-rare -> no wave-amplified replay).
    float bqA = -1.0f, b2A = -1.0f; int ixA = 0;
    float bqB = -1.0f, b2B = -1.0f; int ixB = 0;

#pragma unroll 4
    for (int k = 0; k < 64; ++k) {
        // half A: j = k (wave-uniform -> s_load + LDS broadcast)
        {
            const float4 b = boxes2[k];
            const float a2 = s_area2[k];
            const float hy = fmaxf(fminf(a.z, b.z) - fmaxf(a.x, b.x), 0.0f);
            const float hx = fmaxf(fminf(a.w, b.w) - fmaxf(a.y, b.y), 0.0f);
            const float inter = hy * hx;
            const float um = fmaxf((area1 + a2) - inter, 1e-10f);
            const float q = inter * __builtin_amdgcn_rcpf(um);
            b2A = fmaxf(b2A, fminf(bqA, q));   // runner-up
            const bool cc = q > bqA;           // strict > == first-max
            bqA = fmaxf(bqA, q);
            ixA = cc ? k : ixA;                // inline-const cndmask
        }
        // half B: j = k + 64
        {
            const float4 b = boxes2[k + 64];
            const float a2 = s_area2[k + 64];
            const float hy = fmaxf(fminf(a.z, b.z) - fmaxf(a.x, b.x), 0.0f);
            const float hx = fmaxf(fminf(a.w, b.w) - fmaxf(a.y, b.y), 0.0f);
            const float inter = hy * hx;
            const float um = fmaxf((area1 + a2) - inter, 1e-10f);
            const float q = inter * __builtin_amdgcn_rcpf(um);
            b2B = fmaxf(b2B, fminf(bqB, q));
            const bool cc = q > bqB;
            bqB = fmaxf(bqB, q);
            ixB = cc ? k : ixB;
        }
    }

    // merge halves (A first => strict > keeps earlier index on ties)
    const float top = fmaxf(bqA, bqB);
    const float sec = fmaxf(fminf(bqA, bqB), fmaxf(b2A, b2B));
    int bidx = (bqB > bqA) ? (ixB + 64) : ixA;

    // ambiguous only if global top-2 within the band (covers rcp error and
    // exact-rounded-quotient ties); all-zero windows give top==0 -> no replay
    const bool slow = (top > 0.0f) && ((top - sec) <= top * BAND);

    if (slow) {
        // rare: exact replay with reference semantics over all 128
        float best = -1.0f;
        int   bx = 0;
        for (int j = 0; j < N2; ++j) {
            const float4 b = boxes2[j];
            const float a2 = s_area2[j];
            const float hy = fmaxf(fminf(a.z, b.z) - fmaxf(a.x, b.x), 0.0f);
            const float hx = fmaxf(fminf(a.w, b.w) - fmaxf(a.y, b.y), 0.0f);
            const float inter = hy * hx;
            const float um = fmaxf((area1 + a2) - inter, 1e-10f);
            const float qq = inter / um;       // exact IEEE divide
            if (qq > best) { best = qq; bx = j; }
        }
        bidx = bx;
    }

    // one exact IEEE divide on the winner reproduces matched_val bitwise
    const float4 wb = boxes2[bidx];            // per-lane gather, L1-hot
    const float wa2 = (wb.z - wb.x) * (wb.w - wb.y);   // == reference area2
    const float why = fmaxf(fminf(a.z, wb.z) - fmaxf(a.x, wb.x), 0.0f);
    const float whx = fmaxf(fminf(a.w, wb.w) - fmaxf(a.y, wb.y), 0.0f);
    const float winter = why * whx;
    const float wum = fmaxf((area1 + wa2) - winter, 1e-10f);
    const float qe = winter / wum;

    if (i < n1) {
        out_vals[i]   = qe;
        out_idx[i]    = (float)bidx;
        out_labels[i] = (qe >= 0.7f) ? 1.0f : ((qe < 0.3f) ? 0.0f : -1.0f);
    }
}

extern "C" void kernel_launch(void* const* d_in, const int* in_sizes, int n_in,
                              void* d_out, int out_size, void* d_ws, size_t ws_size,
                              hipStream_t stream) {
    const float4* boxes1 = (const float4*)d_in[0];
    const float4* boxes2 = (const float4*)d_in[1];
    const int n1 = in_sizes[0] / 4;

    float* out = (float*)d_out;
    float* out_vals   = out;
    float* out_idx    = out + n1;
    float* out_labels = out + 2 * n1;

    const int grid = (n1 + BLOCK - 1) / BLOCK;
    matcher_kernel<<<grid, BLOCK, 0, stream>>>(boxes1, boxes2,
                                               out_vals, out_idx, out_labels, n1);
}

// Round 11
// 27.063 us; speedup vs baseline: 3.2968x; 1.3814x over previous
//
#include <hip/hip_runtime.h>

#define N2 128
#define BLOCK 256        // 4 waves; wave w covers j in [32w, 32w+32)
#define APB 128          // anchors per block: 2 per lane (i0 and i0+64)
#define BAND 3.814697265625e-06f   // 2^-18 relative guard band (rcp err ~2^-22)

__global__ __launch_bounds__(BLOCK, 8) void matcher_kernel(
    const float4* __restrict__ boxes1,
    const float4* __restrict__ boxes2,
    float* __restrict__ out_vals,
    float* __restrict__ out_idx,
    float* __restrict__ out_labels,
    int n1)
{
#pragma clang fp contract(off)
    __shared__ float s_area2[N2];
    __shared__ float s_q[4][APB];
    __shared__ int   s_ix[4][APB];

    const int t = threadIdx.x;
    if (t < N2) {
        const float4 b = boxes2[t];            // (y1, x1, y2, x2)
        s_area2[t] = (b.z - b.x) * (b.w - b.y);
    }
    __syncthreads();

    const int w    = __builtin_amdgcn_readfirstlane(t >> 6); // wave id, uniform
    const int lane = t & 63;
    const int i0   = blockIdx.x * APB + lane;
    const int i1   = i0 + 64;

    const float4 a0 = boxes1[(i0 < n1) ? i0 : 0];
    const float4 a1 = boxes1[(i1 < n1) ? i1 : 0];
    const float ar0 = (a0.z - a0.x) * (a0.w - a0.y);
    const float ar1 = (a1.z - a1.x) * (a1.w - a1.y);

    const int j0 = w * 32;
    // argmax of r = inter/S (S = area1+area2) == argmax of ref IoU:
    // q = r/(1-r) is strictly increasing on r in [0, 1/2], and
    // inter <= min(area1,area2) => r <= 1/2. Track top-2 approx r per anchor;
    // band test once post-loop (per-lane-rare => no wave-amplified replay).
    float bq0 = -1.0f, b20 = -1.0f; int bx0 = 0;
    float bq1 = -1.0f, b21 = -1.0f; int bx1 = 0;

#pragma unroll 8
    for (int k = 0; k < 32; ++k) {
        const int j = j0 + k;                  // wave-uniform
        const float4 b = boxes2[j];            // uniform -> s_load_dwordx4
        const float a2 = s_area2[j];           // uniform -> LDS broadcast (b32)
        // anchor 0
        {
            const float hy = fmaxf(fminf(a0.z, b.z) - fmaxf(a0.x, b.x), 0.0f);
            const float hx = fmaxf(fminf(a0.w, b.w) - fmaxf(a0.y, b.y), 0.0f);
            const float inter = hy * hx;
            const float S = ar0 + a2;
            // fmax(...,0) absorbs 0*rcp(0)=NaN (both boxes degenerate) to
            // the reference's q=0 for that pair
            const float q = fmaxf(inter * __builtin_amdgcn_rcpf(S), 0.0f);
            b20 = fmaxf(b20, fminf(bq0, q));   // runner-up
            const bool cc = q > bq0;           // strict > == first-max
            bq0 = fmaxf(bq0, q);
            bx0 = cc ? k : bx0;                // inline-const cndmask
        }
        // anchor 1
        {
            const float hy = fmaxf(fminf(a1.z, b.z) - fmaxf(a1.x, b.x), 0.0f);
            const float hx = fmaxf(fminf(a1.w, b.w) - fmaxf(a1.y, b.y), 0.0f);
            const float inter = hy * hx;
            const float S = ar1 + a2;
            const float q = fmaxf(inter * __builtin_amdgcn_rcpf(S), 0.0f);
            b21 = fmaxf(b21, fminf(bq1, q));
            const bool cc = q > bq1;
            bq1 = fmaxf(bq1, q);
            bx1 = cc ? k : bx1;
        }
    }

    int bidx0 = j0 + bx0;
    int bidx1 = j0 + bx1;
    // ambiguous only if the top-2 approx ratios are within the band
    const bool slow0 = (bq0 > 0.0f) && ((bq0 - b20) <= bq0 * BAND);
    const bool slow1 = (bq1 > 0.0f) && ((bq1 - b21) <= bq1 * BAND);

    // exact reference-semantics IoU for (anchor AA, box J)
#define REFQ(AA, AR, J, QOUT)                                             \
    {                                                                     \
        const float4 b = boxes2[(J)];                                     \
        const float wa2 = (b.z - b.x) * (b.w - b.y);                      \
        const float hy = fmaxf(fminf(AA.z, b.z) - fmaxf(AA.x, b.x), 0.0f);\
        const float hx = fmaxf(fminf(AA.w, b.w) - fmaxf(AA.y, b.y), 0.0f);\
        const float inter = hy * hx;                                      \
        const float um = fmaxf(((AR) + wa2) - inter, 1e-10f);             \
        QOUT = inter / um;                                                \
    }

    if (slow0) {       // rare: exact replay of this wave's window, anchor 0
        float best = -1.0f; int bx = j0;
        for (int k = 0; k < 32; ++k) {
            float qq; REFQ(a0, ar0, j0 + k, qq)
            if (qq > best) { best = qq; bx = j0 + k; }
        }
        bidx0 = bx;
    }
    if (slow1) {
        float best = -1.0f; int bx = j0;
        for (int k = 0; k < 32; ++k) {
            float qq; REFQ(a1, ar1, j0 + k, qq)
            if (qq > best) { best = qq; bx = j0 + k; }
        }
        bidx1 = bx;
    }

    // one exact IEEE divide per winner reproduces matched_val bitwise
    float qe0, qe1;
    REFQ(a0, ar0, bidx0, qe0)
    REFQ(a1, ar1, bidx1, qe1)

    s_q[w][lane]       = qe0;
    s_ix[w][lane]      = bidx0;
    s_q[w][lane + 64]  = qe1;
    s_ix[w][lane + 64] = bidx1;
    __syncthreads();

    // merge the 4 wave-partials; ascending wave + strict > == first-max
    if (t < APB) {
        const int ii = blockIdx.x * APB + t;
        if (ii < n1) {
            float q  = s_q[0][t];
            int   ix = s_ix[0][t];
#pragma unroll
            for (int w2 = 1; w2 < 4; ++w2) {
                const float q2 = s_q[w2][t];
                if (q2 > q) { q = q2; ix = s_ix[w2][t]; }
            }
            out_vals[ii]   = q;
            out_idx[ii]    = (float)ix;
            out_labels[ii] = (q >= 0.7f) ? 1.0f : ((q < 0.3f) ? 0.0f : -1.0f);
        }
    }
}

extern "C" void kernel_launch(void* const* d_in, const int* in_sizes, int n_in,
                              void* d_out, int out_size, void* d_ws, size_t ws_size,
                              hipStream_t stream) {
    const float4* boxes1 = (const float4*)d_in[0];
    const float4* boxes2 = (const float4*)d_in[1];
    const int n1 = in_sizes[0] / 4;

    float* out = (float*)d_out;
    float* out_vals   = out;
    float* out_idx    = out + n1;
    float* out_labels = out + 2 * n1;

    const int grid = (n1 + APB - 1) / APB;
    matcher_kernel<<<grid, BLOCK, 0, stream>>>(boxes1, boxes2,
                                               out_vals, out_idx, out_labels, n1);
}

// Round 12
// 25.717 us; speedup vs baseline: 3.4694x; 1.0524x over previous
//
#include <hip/hip_runtime.h>

#define N2 128
#define BLOCK 512        // 8 waves; wave w covers j in [16w, 16w+16)
#define APB 256          // anchors per block: 4 per lane (l, l+64, l+128, l+192)
#define WIN 16
#define BAND 3.814697265625e-06f   // 2^-18 relative guard band (rcp err ~2^-21)

__global__ __launch_bounds__(BLOCK, 8) void matcher_kernel(
    const float4* __restrict__ boxes1,
    const float4* __restrict__ boxes2,
    float* __restrict__ out_vals,
    float* __restrict__ out_idx,
    float* __restrict__ out_labels,
    int n1)
{
#pragma clang fp contract(off)
    __shared__ float s_area2[N2];
    __shared__ float s_q[8][APB];
    __shared__ int   s_ix[8][APB];

    const int t = threadIdx.x;
    if (t < N2) {
        const float4 b = boxes2[t];            // (y1, x1, y2, x2)
        s_area2[t] = (b.z - b.x) * (b.w - b.y);
    }
    __syncthreads();

    const int w    = __builtin_amdgcn_readfirstlane(t >> 6); // wave id 0..7
    const int lane = t & 63;
    const int base = blockIdx.x * APB;

    // 4 anchors per lane, all statically indexed (full unroll -> registers)
    float4 A[4]; float AR[4];
#pragma unroll
    for (int m = 0; m < 4; ++m) {
        const int i = base + lane + m * 64;
        A[m] = boxes1[(i < n1) ? i : 0];
        AR[m] = (A[m].z - A[m].x) * (A[m].w - A[m].y);
    }

    const int j0 = w * WIN;
    // argmax of r = inter/S (S=area1+area2) == argmax of ref IoU (q=r/(1-r)
    // monotone on r in [0,1/2]); top-2 tracked, band test once post-loop.
    float bq[4] = {-1.0f, -1.0f, -1.0f, -1.0f};
    float b2[4] = {-1.0f, -1.0f, -1.0f, -1.0f};
    int   bx[4] = {0, 0, 0, 0};

#pragma unroll 8
    for (int k = 0; k < WIN; ++k) {
        const int j = j0 + k;                  // wave-uniform
        const float4 b = boxes2[j];            // uniform -> s_load_dwordx4
        const float a2 = s_area2[j];           // uniform -> LDS broadcast
#pragma unroll
        for (int m = 0; m < 4; ++m) {
            const float hy = fmaxf(fminf(A[m].z, b.z) - fmaxf(A[m].x, b.x), 0.0f);
            const float hx = fmaxf(fminf(A[m].w, b.w) - fmaxf(A[m].y, b.y), 0.0f);
            const float inter = hy * hx;
            const float S = AR[m] + a2;
            // fmax(...,0) absorbs 0*rcp(0)=NaN (both degenerate) to ref's q=0
            const float q = fmaxf(inter * __builtin_amdgcn_rcpf(S), 0.0f);
            b2[m] = fmaxf(b2[m], fminf(bq[m], q));   // runner-up
            const bool cc = q > bq[m];               // strict > == first-max
            bq[m] = fmaxf(bq[m], q);
            bx[m] = cc ? k : bx[m];                  // inline-const cndmask
        }
    }

    // exact reference-semantics IoU for (anchor m, global box J)
#define REFQ(M, J, QOUT)                                                   \
    {                                                                      \
        const float4 b = boxes2[(J)];                                      \
        const float wa2 = (b.z - b.x) * (b.w - b.y);                       \
        const float hy = fmaxf(fminf(A[M].z, b.z) - fmaxf(A[M].x, b.x), 0.0f); \
        const float hx = fmaxf(fminf(A[M].w, b.w) - fmaxf(A[M].y, b.y), 0.0f); \
        const float inter = hy * hx;                                       \
        const float um = fmaxf((AR[M] + wa2) - inter, 1e-10f);             \
        QOUT = inter / um;                                                 \
    }

#pragma unroll
    for (int m = 0; m < 4; ++m) {
        int bidx = j0 + bx[m];
        const bool slow = (bq[m] > 0.0f) && ((bq[m] - b2[m]) <= bq[m] * BAND);
        if (slow) {
            // rare: exact replay of this wave's 16-box window
            float best = -1.0f; int bxx = j0;
            for (int k = 0; k < WIN; ++k) {
                float qq; REFQ(m, j0 + k, qq)
                if (qq > best) { best = qq; bxx = j0 + k; }
            }
            bidx = bxx;
        }
        // one exact IEEE divide on the winner: bit-exact matched_val partial
        float qe; REFQ(m, bidx, qe)
        s_q[w][lane + m * 64]  = qe;
        s_ix[w][lane + m * 64] = bidx;
    }
    __syncthreads();

    // merge the 8 wave-partials; ascending wave (ascending j-windows) +
    // strict > on EXACT values == global first-max
    if (t < APB) {
        const int ii = base + t;
        if (ii < n1) {
            float q  = s_q[0][t];
            int   ix = s_ix[0][t];
#pragma unroll
            for (int w2 = 1; w2 < 8; ++w2) {
                const float q2 = s_q[w2][t];
                if (q2 > q) { q = q2; ix = s_ix[w2][t]; }
            }
            out_vals[ii]   = q;
            out_idx[ii]    = (float)ix;
            out_labels[ii] = (q >= 0.7f) ? 1.0f : ((q < 0.3f) ? 0.0f : -1.0f);
        }
    }
}

extern "C" void kernel_launch(void* const* d_in, const int* in_sizes, int n_in,
                              void* d_out, int out_size, void* d_ws, size_t ws_size,
                              hipStream_t stream) {
    const float4* boxes1 = (const float4*)d_in[0];
    const float4* boxes2 = (const float4*)d_in[1];
    const int n1 = in_sizes[0] / 4;

    float* out = (float*)d_out;
    float* out_vals   = out;
    float* out_idx    = out + n1;
    float* out_labels = out + 2 * n1;

    const int grid = (n1 + APB - 1) / APB;
    matcher_kernel<<<grid, BLOCK, 0, stream>>>(boxes1, boxes2,
                                               out_vals, out_idx, out_labels, n1);
}